// Round 1
// baseline (517.379 us; speedup 1.0000x reference)
//
#include <hip/hip_runtime.h>

#define D_FEAT 64

// deg[col[e]] += 1
__global__ void k_deg(const int* __restrict__ col, float* __restrict__ deg, int E) {
    int e = blockIdx.x * blockDim.x + threadIdx.x;
    if (e < E) atomicAdd(&deg[col[e]], 1.0f);
}

// dis[i] = deg>0 ? rsqrt(deg) : 0   (deg is a count, so deg>0 => deg>=1, max(deg,1)=deg)
__global__ void k_dis(const float* __restrict__ deg, float* __restrict__ dis, int n) {
    int i = blockIdx.x * blockDim.x + threadIdx.x;
    if (i < n) {
        float d = deg[i];
        dis[i] = (d > 0.0f) ? rsqrtf(d) : 0.0f;
    }
}

// out = res_scale * x  (float4 streaming init; harness poisons d_out each call)
__global__ void k_resid(const float4* __restrict__ x, float4* __restrict__ out,
                        const float* __restrict__ res_scale_p, int n4) {
    int i = blockIdx.x * blockDim.x + threadIdx.x;
    if (i < n4) {
        float rs = *res_scale_p;
        float4 v = x[i];
        out[i] = make_float4(rs * v.x, rs * v.y, rs * v.z, rs * v.w);
    }
}

// One wave per edge, one lane per feature:
// out[col*64 + f] += alpha * dis[row] * dis[col] * x[row*64 + f]
__global__ void k_scatter(const float* __restrict__ x,
                          const int* __restrict__ row,
                          const int* __restrict__ col,
                          const float* __restrict__ dis,
                          const float* __restrict__ alpha_p,
                          float* __restrict__ out, int E) {
    int gid = blockIdx.x * blockDim.x + threadIdx.x;
    int e = gid >> 6;        // edge index (wave-uniform)
    int f = gid & 63;        // feature index (lane)
    if (e >= E) return;
    int r = row[e];          // same addr across wave -> broadcast from cache
    int c = col[e];
    float norm = (*alpha_p) * dis[r] * dis[c];
    float v = x[(long long)r * D_FEAT + f] * norm;   // coalesced 256B gather
    atomicAdd(&out[(long long)c * D_FEAT + f], v);   // coalesced 4-line atomic
}

extern "C" void kernel_launch(void* const* d_in, const int* in_sizes, int n_in,
                              void* d_out, int out_size, void* d_ws, size_t ws_size,
                              hipStream_t stream) {
    const float* x         = (const float*)d_in[0];
    const float* alpha     = (const float*)d_in[1];
    const float* res_scale = (const float*)d_in[2];
    const int*   ei        = (const int*)d_in[3];

    const int n = in_sizes[0] / D_FEAT;      // 100000
    const int E = in_sizes[3] / 2;           // 1600000
    const int* row = ei;                     // edge_index[0] = source
    const int* col = ei + E;                 // edge_index[1] = target

    float* out = (float*)d_out;
    float* deg = (float*)d_ws;               // n floats
    float* dis = deg + n;                    // n floats

    hipMemsetAsync(deg, 0, (size_t)n * sizeof(float), stream);

    k_deg<<<(E + 255) / 256, 256, 0, stream>>>(col, deg, E);
    k_dis<<<(n + 255) / 256, 256, 0, stream>>>(deg, dis, n);

    const int n4 = n * D_FEAT / 4;
    k_resid<<<(n4 + 255) / 256, 256, 0, stream>>>((const float4*)x, (float4*)out,
                                                  res_scale, n4);

    const long long total = (long long)E * D_FEAT;
    const int blocks = (int)((total + 255) / 256);
    k_scatter<<<blocks, 256, 0, stream>>>(x, row, col, dis, alpha, out, E);
}

// Round 2
// 429.410 us; speedup vs baseline: 1.2049x; 1.2049x over previous
//
#include <hip/hip_runtime.h>

#define D_FEAT 64

// ---------------- degree histogram: deg[col[e]] += 1 ----------------
__global__ void k_deg(const int* __restrict__ col, int* __restrict__ deg, int E) {
    int e = blockIdx.x * blockDim.x + threadIdx.x;
    if (e < E) atomicAdd(&deg[col[e]], 1);
}

// ---------------- dis[i] = deg>0 ? rsqrt(deg) : 0 ----------------
__global__ void k_dis(const int* __restrict__ deg, float* __restrict__ dis, int n) {
    int i = blockIdx.x * blockDim.x + threadIdx.x;
    if (i < n) {
        int d = deg[i];
        dis[i] = (d > 0) ? rsqrtf((float)d) : 0.0f;
    }
}

// ---------------- single-block chunked exclusive scan ----------------
// start[i] = sum_{j<i} deg[j];  start[n] = E;  cursor[i] = start[i]
__global__ __launch_bounds__(1024) void k_scan(const int* __restrict__ deg,
                                               int* __restrict__ start,
                                               int* __restrict__ cursor, int n) {
    __shared__ int wsum[16];
    __shared__ int s_carry;
    const int tid  = threadIdx.x;
    const int lane = tid & 63;
    const int wv   = tid >> 6;
    if (tid == 0) s_carry = 0;
    __syncthreads();
    for (int base = 0; base < n; base += 1024) {
        int i = base + tid;
        int v = (i < n) ? deg[i] : 0;
        // inclusive scan within wave (shfl, no barriers)
        int s = v;
        #pragma unroll
        for (int off = 1; off < 64; off <<= 1) {
            int t = __shfl_up(s, off, 64);
            if (lane >= off) s += t;
        }
        if (lane == 63) wsum[wv] = s;
        __syncthreads();
        // wave 0 turns the 16 wave totals into exclusive offsets
        if (wv == 0) {
            int ws = (lane < 16) ? wsum[lane] : 0;
            int t = ws;
            #pragma unroll
            for (int off = 1; off < 16; off <<= 1) {
                int u = __shfl_up(t, off, 64);
                if (lane >= off) t += u;
            }
            if (lane < 16) wsum[lane] = t - ws;   // exclusive wave offset
        }
        __syncthreads();
        int carry = s_carry;
        int excl  = carry + wsum[wv] + (s - v);
        if (i < n) { start[i] = excl; cursor[i] = excl; }
        __syncthreads();   // everyone done reading s_carry/wsum
        if (tid == 1023) s_carry = carry + wsum[15] + s;  // += chunk total
        __syncthreads();
    }
    if (threadIdx.x == 0) start[n] = s_carry;
}

// ---------------- bucket fill: CSR by target, with precomputed weight ----------------
__global__ void k_build(const int* __restrict__ row, const int* __restrict__ col,
                        const float* __restrict__ dis, int* __restrict__ cursor,
                        int* __restrict__ csr_src, float* __restrict__ csr_w, int E) {
    int e = blockIdx.x * blockDim.x + threadIdx.x;
    if (e >= E) return;
    int r = row[e];
    int c = col[e];
    int pos = atomicAdd(&cursor[c], 1);
    csr_src[pos] = r;
    csr_w[pos]   = dis[r] * dis[c];
}

// ---------------- gather: one wave per node, lane = feature ----------------
// out[i*64+f] = alpha * sum_k w_k * x[src_k*64+f] + res_scale * x[i*64+f]
__global__ void k_gather(const float* __restrict__ x,
                         const int* __restrict__ start,
                         const int* __restrict__ csr_src,
                         const float* __restrict__ csr_w,
                         const float* __restrict__ alpha_p,
                         const float* __restrict__ rs_p,
                         float* __restrict__ out, int n) {
    int wid = (blockIdx.x * blockDim.x + threadIdx.x) >> 6;
    int f   = threadIdx.x & 63;
    if (wid >= n) return;
    int s = start[wid];
    int e = start[wid + 1];
    float acc = 0.0f;
    int k = s;
    for (; k + 1 < e; k += 2) {     // 2-way unroll for memory-level parallelism
        int   s0 = csr_src[k],  s1 = csr_src[k + 1];
        float w0 = csr_w[k],    w1 = csr_w[k + 1];
        float v0 = x[(size_t)s0 * D_FEAT + f];
        float v1 = x[(size_t)s1 * D_FEAT + f];
        acc = fmaf(w0, v0, acc);
        acc = fmaf(w1, v1, acc);
    }
    if (k < e)
        acc = fmaf(csr_w[k], x[(size_t)csr_src[k] * D_FEAT + f], acc);
    out[(size_t)wid * D_FEAT + f] =
        (*alpha_p) * acc + (*rs_p) * x[(size_t)wid * D_FEAT + f];
}

extern "C" void kernel_launch(void* const* d_in, const int* in_sizes, int n_in,
                              void* d_out, int out_size, void* d_ws, size_t ws_size,
                              hipStream_t stream) {
    const float* x         = (const float*)d_in[0];
    const float* alpha     = (const float*)d_in[1];
    const float* res_scale = (const float*)d_in[2];
    const int*   ei        = (const int*)d_in[3];

    const int n = in_sizes[0] / D_FEAT;      // 100000
    const int E = in_sizes[3] / 2;           // 1600000
    const int* row = ei;                     // sources
    const int* col = ei + E;                 // targets

    float* out = (float*)d_out;

    // workspace layout
    char* ws = (char*)d_ws;
    int*   deg     = (int*)ws;                       ws += (size_t)n * 4;
    float* dis     = (float*)ws;                     ws += (size_t)n * 4;
    int*   start   = (int*)ws;                       ws += (size_t)(n + 1) * 4;
    int*   cursor  = (int*)ws;                       ws += (size_t)n * 4;
    int*   csr_src = (int*)ws;                       ws += (size_t)E * 4;
    float* csr_w   = (float*)ws;                     /* E * 4 */

    hipMemsetAsync(deg, 0, (size_t)n * sizeof(int), stream);

    k_deg <<<(E + 255) / 256, 256, 0, stream>>>(col, deg, E);
    k_dis <<<(n + 255) / 256, 256, 0, stream>>>(deg, dis, n);
    k_scan<<<1, 1024, 0, stream>>>(deg, start, cursor, n);
    k_build<<<(E + 255) / 256, 256, 0, stream>>>(row, col, dis, cursor,
                                                 csr_src, csr_w, E);

    const long long total = (long long)n * D_FEAT;
    const int blocks = (int)((total + 255) / 256);
    k_gather<<<blocks, 256, 0, stream>>>(x, start, csr_src, csr_w,
                                         alpha, res_scale, out, n);
}

// Round 3
// 339.890 us; speedup vs baseline: 1.5222x; 1.2634x over previous
//
#include <hip/hip_runtime.h>

#define D_FEAT 64

// ---- pass 1: deg histogram, AND record each edge's within-bucket rank ----
__global__ void k_deg_rank(const int* __restrict__ col, int* __restrict__ deg,
                           int* __restrict__ rank, int E) {
    int e = blockIdx.x * blockDim.x + threadIdx.x;
    if (e < E) rank[e] = atomicAdd(&deg[col[e]], 1);
}

// ---- single-block chunked exclusive scan; fuses dis = rsqrt(deg) ----
// start[i] = sum_{j<i} deg[j];  start[n] = E
__global__ __launch_bounds__(1024) void k_scan(const int* __restrict__ deg,
                                               int* __restrict__ start,
                                               float* __restrict__ dis, int n) {
    __shared__ int wsum[16];
    __shared__ int s_carry;
    const int tid  = threadIdx.x;
    const int lane = tid & 63;
    const int wv   = tid >> 6;
    if (tid == 0) s_carry = 0;
    __syncthreads();
    for (int base = 0; base < n; base += 1024) {
        int i = base + tid;
        int v = (i < n) ? deg[i] : 0;
        int s = v;
        #pragma unroll
        for (int off = 1; off < 64; off <<= 1) {
            int t = __shfl_up(s, off, 64);
            if (lane >= off) s += t;
        }
        if (lane == 63) wsum[wv] = s;
        __syncthreads();
        if (wv == 0) {
            int ws = (lane < 16) ? wsum[lane] : 0;
            int t = ws;
            #pragma unroll
            for (int off = 1; off < 16; off <<= 1) {
                int u = __shfl_up(t, off, 64);
                if (lane >= off) t += u;
            }
            if (lane < 16) wsum[lane] = t - ws;   // exclusive wave offset
        }
        __syncthreads();
        int carry = s_carry;
        if (i < n) {
            start[i] = carry + wsum[wv] + (s - v);
            dis[i]   = (v > 0) ? rsqrtf((float)v) : 0.0f;
        }
        __syncthreads();
        if (tid == 1023) s_carry = carry + wsum[15] + s;
        __syncthreads();
    }
    if (threadIdx.x == 0) start[n] = s_carry;
}

// ---- pass 2: atomic-free CSR fill ----
// csr_src[start[col[e]] + rank[e]] = row[e]
__global__ void k_fill(const int* __restrict__ row, const int* __restrict__ col,
                       const int* __restrict__ rank, const int* __restrict__ start,
                       int* __restrict__ csr_src, int E) {
    int e = blockIdx.x * blockDim.x + threadIdx.x;
    if (e >= E) return;
    int c = col[e];                       // coalesced
    int rk = rank[e];                     // coalesced
    int pos = start[c] + rk;              // random 4B read, L2-resident (400KB)
    csr_src[pos] = row[e];                // scattered 4B write
}

// ---- gather: one wave per node, lane = feature ----
// out[i][f] = alpha * dis[i] * sum_k dis[src_k] * x[src_k][f] + rs * x[i][f]
__global__ void k_gather(const float* __restrict__ x,
                         const int* __restrict__ start,
                         const int* __restrict__ csr_src,
                         const float* __restrict__ dis,
                         const float* __restrict__ alpha_p,
                         const float* __restrict__ rs_p,
                         float* __restrict__ out, int n) {
    int wid = (blockIdx.x * blockDim.x + threadIdx.x) >> 6;
    int f   = threadIdx.x & 63;
    if (wid >= n) return;
    int s = start[wid];
    int e = start[wid + 1];
    float acc = 0.0f;
    int k = s;
    // 4-way unroll: 4 independent gather chains in flight
    for (; k + 3 < e; k += 4) {
        int   s0 = csr_src[k],     s1 = csr_src[k + 1];
        int   s2 = csr_src[k + 2], s3 = csr_src[k + 3];
        float w0 = dis[s0], w1 = dis[s1], w2 = dis[s2], w3 = dis[s3];
        float v0 = x[(size_t)s0 * D_FEAT + f];
        float v1 = x[(size_t)s1 * D_FEAT + f];
        float v2 = x[(size_t)s2 * D_FEAT + f];
        float v3 = x[(size_t)s3 * D_FEAT + f];
        acc = fmaf(w0, v0, acc);
        acc = fmaf(w1, v1, acc);
        acc = fmaf(w2, v2, acc);
        acc = fmaf(w3, v3, acc);
    }
    for (; k < e; ++k) {
        int si = csr_src[k];
        acc = fmaf(dis[si], x[(size_t)si * D_FEAT + f], acc);
    }
    out[(size_t)wid * D_FEAT + f] =
        (*alpha_p) * dis[wid] * acc + (*rs_p) * x[(size_t)wid * D_FEAT + f];
}

extern "C" void kernel_launch(void* const* d_in, const int* in_sizes, int n_in,
                              void* d_out, int out_size, void* d_ws, size_t ws_size,
                              hipStream_t stream) {
    const float* x         = (const float*)d_in[0];
    const float* alpha     = (const float*)d_in[1];
    const float* res_scale = (const float*)d_in[2];
    const int*   ei        = (const int*)d_in[3];

    const int n = in_sizes[0] / D_FEAT;      // 100000
    const int E = in_sizes[3] / 2;           // 1600000
    const int* row = ei;                     // sources
    const int* col = ei + E;                 // targets

    float* out = (float*)d_out;

    // workspace layout
    char* ws = (char*)d_ws;
    int*   deg     = (int*)ws;     ws += (size_t)n * 4;
    float* dis     = (float*)ws;   ws += (size_t)n * 4;
    int*   start   = (int*)ws;     ws += (size_t)(n + 1) * 4;
    int*   rank    = (int*)ws;     ws += (size_t)E * 4;
    int*   csr_src = (int*)ws;     /* E * 4 */

    hipMemsetAsync(deg, 0, (size_t)n * sizeof(int), stream);

    k_deg_rank<<<(E + 255) / 256, 256, 0, stream>>>(col, deg, rank, E);
    k_scan    <<<1, 1024, 0, stream>>>(deg, start, dis, n);
    k_fill    <<<(E + 255) / 256, 256, 0, stream>>>(row, col, rank, start,
                                                    csr_src, E);

    const long long total = (long long)n * D_FEAT;
    const int blocks = (int)((total + 255) / 256);
    k_gather<<<blocks, 256, 0, stream>>>(x, start, csr_src, dis,
                                         alpha, res_scale, out, n);
}

// Round 4
// 252.859 us; speedup vs baseline: 2.0461x; 1.3442x over previous
//
#include <hip/hip_runtime.h>

#define D_FEAT 64
#define SCAN_BLOCK 1024
#define SCAN_VPT 4
#define SCAN_CHUNK (SCAN_BLOCK * SCAN_VPT)   // 4096 elements per block

// ---- pass 1: deg histogram, AND record each edge's within-bucket rank ----
__global__ void k_deg_rank(const int* __restrict__ col, int* __restrict__ deg,
                           int* __restrict__ rank, int E) {
    int e = blockIdx.x * blockDim.x + threadIdx.x;
    if (e < E) rank[e] = atomicAdd(&deg[col[e]], 1);
}

// ---- scan phase A: per-block sums of deg ----
__global__ __launch_bounds__(1024) void k_part(const int* __restrict__ deg,
                                               int* __restrict__ bsum, int n) {
    __shared__ int ws[16];
    const int lane = threadIdx.x & 63, wv = threadIdx.x >> 6;
    int base = blockIdx.x * SCAN_CHUNK + threadIdx.x * SCAN_VPT;
    int s = 0;
    #pragma unroll
    for (int j = 0; j < SCAN_VPT; ++j) {
        int i = base + j;
        if (i < n) s += deg[i];
    }
    #pragma unroll
    for (int off = 32; off; off >>= 1) s += __shfl_down(s, off, 64);
    if (lane == 0) ws[wv] = s;
    __syncthreads();
    if (threadIdx.x == 0) {
        int t = 0;
        #pragma unroll
        for (int k = 0; k < 16; ++k) t += ws[k];
        bsum[blockIdx.x] = t;
    }
}

// ---- scan phase B: one wave scans the block sums (in place -> exclusive) ----
__global__ void k_scan_bsums(int* __restrict__ bsum, int* __restrict__ start,
                             int B, int n) {
    const int lane = threadIdx.x;   // 64 threads
    int carry = 0;
    for (int base = 0; base < B; base += 64) {
        int i = base + lane;
        int v = (i < B) ? bsum[i] : 0;
        int s = v;
        #pragma unroll
        for (int off = 1; off < 64; off <<= 1) {
            int t = __shfl_up(s, off, 64);
            if (lane >= off) s += t;
        }
        if (i < B) bsum[i] = carry + s - v;     // exclusive + carry
        carry += __shfl(s, 63, 64);             // chunk total
    }
    if (lane == 0) start[n] = carry;            // == E
}

// ---- scan phase C: local exclusive scan + block offset; fused dis ----
__global__ __launch_bounds__(1024) void k_apply(const int* __restrict__ deg,
                                                const int* __restrict__ bsum,
                                                int* __restrict__ start,
                                                float* __restrict__ dis, int n) {
    __shared__ int wsum[16];
    const int lane = threadIdx.x & 63, wv = threadIdx.x >> 6;
    int base = blockIdx.x * SCAN_CHUNK + threadIdx.x * SCAN_VPT;
    int v[SCAN_VPT];
    int tsum = 0;
    #pragma unroll
    for (int j = 0; j < SCAN_VPT; ++j) {
        int i = base + j;
        v[j] = (i < n) ? deg[i] : 0;
        tsum += v[j];
    }
    int s = tsum;   // inclusive wave scan of per-thread sums
    #pragma unroll
    for (int off = 1; off < 64; off <<= 1) {
        int t = __shfl_up(s, off, 64);
        if (lane >= off) s += t;
    }
    if (lane == 63) wsum[wv] = s;
    __syncthreads();
    if (wv == 0) {
        int wsv = (lane < 16) ? wsum[lane] : 0;
        int t = wsv;
        #pragma unroll
        for (int off = 1; off < 16; off <<= 1) {
            int u = __shfl_up(t, off, 64);
            if (lane >= off) t += u;
        }
        if (lane < 16) wsum[lane] = t - wsv;    // exclusive wave offsets
    }
    __syncthreads();
    int excl = bsum[blockIdx.x] + wsum[wv] + (s - tsum);
    #pragma unroll
    for (int j = 0; j < SCAN_VPT; ++j) {
        int i = base + j;
        if (i < n) {
            start[i] = excl;
            dis[i]   = (v[j] > 0) ? rsqrtf((float)v[j]) : 0.0f;
            excl += v[j];
        }
    }
}

// ---- CSR fill (atomic-free) ----
__global__ void k_fill(const int* __restrict__ row, const int* __restrict__ col,
                       const int* __restrict__ rank, const int* __restrict__ start,
                       int* __restrict__ csr_src, int E) {
    int e = blockIdx.x * blockDim.x + threadIdx.x;
    if (e >= E) return;
    int c = col[e];
    int rk = rank[e];
    csr_src[start[c] + rk] = row[e];
}

// ---- gather: one wave per node, lane = feature ----
__global__ void k_gather(const float* __restrict__ x,
                         const int* __restrict__ start,
                         const int* __restrict__ csr_src,
                         const float* __restrict__ dis,
                         const float* __restrict__ alpha_p,
                         const float* __restrict__ rs_p,
                         float* __restrict__ out, int n) {
    int wid = (blockIdx.x * blockDim.x + threadIdx.x) >> 6;
    int f   = threadIdx.x & 63;
    if (wid >= n) return;
    int s = start[wid];
    int e = start[wid + 1];
    float acc = 0.0f;
    int k = s;
    for (; k + 3 < e; k += 4) {
        int   s0 = csr_src[k],     s1 = csr_src[k + 1];
        int   s2 = csr_src[k + 2], s3 = csr_src[k + 3];
        float w0 = dis[s0], w1 = dis[s1], w2 = dis[s2], w3 = dis[s3];
        float v0 = x[(size_t)s0 * D_FEAT + f];
        float v1 = x[(size_t)s1 * D_FEAT + f];
        float v2 = x[(size_t)s2 * D_FEAT + f];
        float v3 = x[(size_t)s3 * D_FEAT + f];
        acc = fmaf(w0, v0, acc);
        acc = fmaf(w1, v1, acc);
        acc = fmaf(w2, v2, acc);
        acc = fmaf(w3, v3, acc);
    }
    for (; k < e; ++k) {
        int si = csr_src[k];
        acc = fmaf(dis[si], x[(size_t)si * D_FEAT + f], acc);
    }
    out[(size_t)wid * D_FEAT + f] =
        (*alpha_p) * dis[wid] * acc + (*rs_p) * x[(size_t)wid * D_FEAT + f];
}

extern "C" void kernel_launch(void* const* d_in, const int* in_sizes, int n_in,
                              void* d_out, int out_size, void* d_ws, size_t ws_size,
                              hipStream_t stream) {
    const float* x         = (const float*)d_in[0];
    const float* alpha     = (const float*)d_in[1];
    const float* res_scale = (const float*)d_in[2];
    const int*   ei        = (const int*)d_in[3];

    const int n = in_sizes[0] / D_FEAT;      // 100000
    const int E = in_sizes[3] / 2;           // 1600000
    const int* row = ei;                     // sources
    const int* col = ei + E;                 // targets

    float* out = (float*)d_out;

    const int B = (n + SCAN_CHUNK - 1) / SCAN_CHUNK;   // 25

    // workspace layout
    char* ws = (char*)d_ws;
    int*   deg     = (int*)ws;     ws += (size_t)n * 4;
    float* dis     = (float*)ws;   ws += (size_t)n * 4;
    int*   start   = (int*)ws;     ws += (size_t)(n + 1) * 4;
    int*   bsum    = (int*)ws;     ws += (size_t)((B + 63) & ~63) * 4;
    int*   rank    = (int*)ws;     ws += (size_t)E * 4;
    int*   csr_src = (int*)ws;     /* E * 4 */

    hipMemsetAsync(deg, 0, (size_t)n * sizeof(int), stream);

    k_deg_rank  <<<(E + 255) / 256, 256, 0, stream>>>(col, deg, rank, E);
    k_part      <<<B, SCAN_BLOCK, 0, stream>>>(deg, bsum, n);
    k_scan_bsums<<<1, 64, 0, stream>>>(bsum, start, B, n);
    k_apply     <<<B, SCAN_BLOCK, 0, stream>>>(deg, bsum, start, dis, n);
    k_fill      <<<(E + 255) / 256, 256, 0, stream>>>(row, col, rank, start,
                                                      csr_src, E);

    const long long total = (long long)n * D_FEAT;
    const int blocks = (int)((total + 255) / 256);
    k_gather<<<blocks, 256, 0, stream>>>(x, start, csr_src, dis,
                                         alpha, res_scale, out, n);
}

// Round 5
// 248.960 us; speedup vs baseline: 2.0782x; 1.0157x over previous
//
#include <hip/hip_runtime.h>
#include <hip/hip_bf16.h>

#define D_FEAT 64
#define SCAN_BLOCK 1024
#define SCAN_VPT 4
#define SCAN_CHUNK (SCAN_BLOCK * SCAN_VPT)   // 4096 elements per block

typedef unsigned int uint32;
typedef unsigned short ushort16;

// ---- fused: bf16 cast of x  +  deg histogram with per-edge rank ----
// t < nhalf: xb[t] = bf16x2(x2[t]);   t < E: rank[t] = deg[col[t]]++
__global__ void k_prep(const float2* __restrict__ x2, uint32* __restrict__ xb,
                       const int* __restrict__ col, int* __restrict__ deg,
                       int* __restrict__ rank, int nhalf, int E) {
    int t = blockIdx.x * blockDim.x + threadIdx.x;
    if (t < E) rank[t] = atomicAdd(&deg[col[t]], 1);
    if (t < nhalf) {
        float2 v = x2[t];
        __hip_bfloat16 bx = __float2bfloat16(v.x);
        __hip_bfloat16 by = __float2bfloat16(v.y);
        uint32 ux = *reinterpret_cast<ushort16*>(&bx);
        uint32 uy = *reinterpret_cast<ushort16*>(&by);
        xb[t] = ux | (uy << 16);
    }
}

// ---- scan phase A: per-block sums of deg ----
__global__ __launch_bounds__(1024) void k_part(const int* __restrict__ deg,
                                               int* __restrict__ bsum, int n) {
    __shared__ int ws[16];
    const int lane = threadIdx.x & 63, wv = threadIdx.x >> 6;
    int base = blockIdx.x * SCAN_CHUNK + threadIdx.x * SCAN_VPT;
    int s = 0;
    #pragma unroll
    for (int j = 0; j < SCAN_VPT; ++j) {
        int i = base + j;
        if (i < n) s += deg[i];
    }
    #pragma unroll
    for (int off = 32; off; off >>= 1) s += __shfl_down(s, off, 64);
    if (lane == 0) ws[wv] = s;
    __syncthreads();
    if (threadIdx.x == 0) {
        int t = 0;
        #pragma unroll
        for (int k = 0; k < 16; ++k) t += ws[k];
        bsum[blockIdx.x] = t;
    }
}

// ---- scan phase B: one wave scans the block sums (exclusive, in place) ----
__global__ void k_scan_bsums(int* __restrict__ bsum, int* __restrict__ start,
                             int B, int n) {
    const int lane = threadIdx.x;   // 64 threads
    int carry = 0;
    for (int base = 0; base < B; base += 64) {
        int i = base + lane;
        int v = (i < B) ? bsum[i] : 0;
        int s = v;
        #pragma unroll
        for (int off = 1; off < 64; off <<= 1) {
            int t = __shfl_up(s, off, 64);
            if (lane >= off) s += t;
        }
        if (i < B) bsum[i] = carry + s - v;
        carry += __shfl(s, 63, 64);
    }
    if (lane == 0) start[n] = carry;            // == E
}

// ---- scan phase C: local exclusive scan + block offset; fused dis ----
__global__ __launch_bounds__(1024) void k_apply(const int* __restrict__ deg,
                                                const int* __restrict__ bsum,
                                                int* __restrict__ start,
                                                float* __restrict__ dis, int n) {
    __shared__ int wsum[16];
    const int lane = threadIdx.x & 63, wv = threadIdx.x >> 6;
    int base = blockIdx.x * SCAN_CHUNK + threadIdx.x * SCAN_VPT;
    int v[SCAN_VPT];
    int tsum = 0;
    #pragma unroll
    for (int j = 0; j < SCAN_VPT; ++j) {
        int i = base + j;
        v[j] = (i < n) ? deg[i] : 0;
        tsum += v[j];
    }
    int s = tsum;
    #pragma unroll
    for (int off = 1; off < 64; off <<= 1) {
        int t = __shfl_up(s, off, 64);
        if (lane >= off) s += t;
    }
    if (lane == 63) wsum[wv] = s;
    __syncthreads();
    if (wv == 0) {
        int wsv = (lane < 16) ? wsum[lane] : 0;
        int t = wsv;
        #pragma unroll
        for (int off = 1; off < 16; off <<= 1) {
            int u = __shfl_up(t, off, 64);
            if (lane >= off) t += u;
        }
        if (lane < 16) wsum[lane] = t - wsv;
    }
    __syncthreads();
    int excl = bsum[blockIdx.x] + wsum[wv] + (s - tsum);
    #pragma unroll
    for (int j = 0; j < SCAN_VPT; ++j) {
        int i = base + j;
        if (i < n) {
            start[i] = excl;
            dis[i]   = (v[j] > 0) ? rsqrtf((float)v[j]) : 0.0f;
            excl += v[j];
        }
    }
}

// ---- CSR fill (atomic-free) ----
__global__ void k_fill(const int* __restrict__ row, const int* __restrict__ col,
                       const int* __restrict__ rank, const int* __restrict__ start,
                       int* __restrict__ csr_src, int E) {
    int e = blockIdx.x * blockDim.x + threadIdx.x;
    if (e >= E) return;
    csr_src[start[col[e]] + rank[e]] = row[e];
}

// ---- gather v2: one wave per node, 2 edges per wave, bf16 messages ----
// lane = (half, l): half = edge parity within pair, l = feature-pair (2l,2l+1)
__global__ void k_gather_bf16(const uint32* __restrict__ xb,
                              const float2* __restrict__ x2,
                              const int* __restrict__ start,
                              const int* __restrict__ csr_src,
                              const float* __restrict__ dis,
                              const float* __restrict__ alpha_p,
                              const float* __restrict__ rs_p,
                              float2* __restrict__ out2, int n) {
    int wid = (blockIdx.x * blockDim.x + threadIdx.x) >> 6;
    if (wid >= n) return;
    const int lane = threadIdx.x & 63;
    const int half = lane >> 5;
    const int l    = lane & 31;
    int s = start[wid];
    int e = start[wid + 1];
    float accx = 0.0f, accy = 0.0f;
    int k0 = s;
    for (; k0 + 4 <= e; k0 += 4) {            // 4 edges/iter (2 per half)
        int s1 = csr_src[k0 + half];
        int s2 = csr_src[k0 + 2 + half];
        float w1 = dis[s1], w2 = dis[s2];
        uint32 p1 = xb[(size_t)s1 * 32 + l];
        uint32 p2 = xb[(size_t)s2 * 32 + l];
        accx = fmaf(w1, __uint_as_float(p1 << 16), accx);
        accy = fmaf(w1, __uint_as_float(p1 & 0xffff0000u), accy);
        accx = fmaf(w2, __uint_as_float(p2 << 16), accx);
        accy = fmaf(w2, __uint_as_float(p2 & 0xffff0000u), accy);
    }
    for (; k0 < e; k0 += 2) {                 // 0-3 remaining edges
        int kk = k0 + half;
        if (kk < e) {
            int s1 = csr_src[kk];
            float w1 = dis[s1];
            uint32 p1 = xb[(size_t)s1 * 32 + l];
            accx = fmaf(w1, __uint_as_float(p1 << 16), accx);
            accy = fmaf(w1, __uint_as_float(p1 & 0xffff0000u), accy);
        }
    }
    accx += __shfl_down(accx, 32, 64);        // fold upper half into lower
    accy += __shfl_down(accy, 32, 64);
    if (half == 0) {
        float adw = (*alpha_p) * dis[wid];
        float rs  = *rs_p;
        float2 xr = x2[(size_t)wid * 32 + l];
        float2 o;
        o.x = fmaf(adw, accx, rs * xr.x);
        o.y = fmaf(adw, accy, rs * xr.y);
        out2[(size_t)wid * 32 + l] = o;
    }
}

// ---- fp32 fallback gather (round-4 kernel), used if ws too small for xb ----
__global__ void k_gather_f32(const float* __restrict__ x,
                             const int* __restrict__ start,
                             const int* __restrict__ csr_src,
                             const float* __restrict__ dis,
                             const float* __restrict__ alpha_p,
                             const float* __restrict__ rs_p,
                             float* __restrict__ out, int n) {
    int wid = (blockIdx.x * blockDim.x + threadIdx.x) >> 6;
    int f   = threadIdx.x & 63;
    if (wid >= n) return;
    int s = start[wid];
    int e = start[wid + 1];
    float acc = 0.0f;
    int k = s;
    for (; k + 3 < e; k += 4) {
        int   s0 = csr_src[k],     s1 = csr_src[k + 1];
        int   s2 = csr_src[k + 2], s3 = csr_src[k + 3];
        float w0 = dis[s0], w1 = dis[s1], w2 = dis[s2], w3 = dis[s3];
        float v0 = x[(size_t)s0 * D_FEAT + f];
        float v1 = x[(size_t)s1 * D_FEAT + f];
        float v2 = x[(size_t)s2 * D_FEAT + f];
        float v3 = x[(size_t)s3 * D_FEAT + f];
        acc = fmaf(w0, v0, acc); acc = fmaf(w1, v1, acc);
        acc = fmaf(w2, v2, acc); acc = fmaf(w3, v3, acc);
    }
    for (; k < e; ++k) {
        int si = csr_src[k];
        acc = fmaf(dis[si], x[(size_t)si * D_FEAT + f], acc);
    }
    out[(size_t)wid * D_FEAT + f] =
        (*alpha_p) * dis[wid] * acc + (*rs_p) * x[(size_t)wid * D_FEAT + f];
}

// plain histogram (fallback path uses same k_prep minus cast? keep k_prep generic)

extern "C" void kernel_launch(void* const* d_in, const int* in_sizes, int n_in,
                              void* d_out, int out_size, void* d_ws, size_t ws_size,
                              hipStream_t stream) {
    const float* x         = (const float*)d_in[0];
    const float* alpha     = (const float*)d_in[1];
    const float* res_scale = (const float*)d_in[2];
    const int*   ei        = (const int*)d_in[3];

    const int n = in_sizes[0] / D_FEAT;      // 100000
    const int E = in_sizes[3] / 2;           // 1600000
    const int* row = ei;                     // sources
    const int* col = ei + E;                 // targets

    float* out = (float*)d_out;
    const int B = (n + SCAN_CHUNK - 1) / SCAN_CHUNK;
    const int Bpad = (B + 63) & ~63;

    // workspace layout
    char* ws = (char*)d_ws;
    int*    deg     = (int*)ws;     ws += (size_t)n * 4;
    float*  dis     = (float*)ws;   ws += (size_t)n * 4;
    int*    start   = (int*)ws;     ws += (size_t)(n + 1) * 4;
    int*    bsum    = (int*)ws;     ws += (size_t)Bpad * 4;
    int*    rank    = (int*)ws;     ws += (size_t)E * 4;
    int*    csr_src = (int*)ws;     ws += (size_t)E * 4;
    uint32* xb      = (uint32*)ws;  // n * 32 uints = n*128 bytes

    const size_t need_bf16 =
        (size_t)n * 4 * 3 + 4 + (size_t)Bpad * 4 + (size_t)E * 8 + (size_t)n * 128;
    const bool bf16_path = (ws_size >= need_bf16);

    hipMemsetAsync(deg, 0, (size_t)n * sizeof(int), stream);

    const int nhalf = n * (D_FEAT / 2);      // float2 / bf16x2 elements
    if (bf16_path) {
        int prep_threads = (nhalf > E) ? nhalf : E;
        k_prep<<<(prep_threads + 255) / 256, 256, 0, stream>>>(
            (const float2*)x, xb, col, deg, rank, nhalf, E);
    } else {
        // histogram only (no cast target space)
        k_prep<<<(E + 255) / 256, 256, 0, stream>>>(
            (const float2*)x, nullptr, col, deg, rank, 0, E);
    }

    k_part      <<<B, SCAN_BLOCK, 0, stream>>>(deg, bsum, n);
    k_scan_bsums<<<1, 64, 0, stream>>>(bsum, start, B, n);
    k_apply     <<<B, SCAN_BLOCK, 0, stream>>>(deg, bsum, start, dis, n);
    k_fill      <<<(E + 255) / 256, 256, 0, stream>>>(row, col, rank, start,
                                                      csr_src, E);

    const long long total = (long long)n * D_FEAT;
    const int blocks = (int)((total + 255) / 256);
    if (bf16_path) {
        k_gather_bf16<<<blocks, 256, 0, stream>>>(xb, (const float2*)x, start,
                                                  csr_src, dis, alpha, res_scale,
                                                  (float2*)out, n);
    } else {
        k_gather_f32<<<blocks, 256, 0, stream>>>(x, start, csr_src, dis,
                                                 alpha, res_scale, out, n);
    }
}

// Round 6
// 239.702 us; speedup vs baseline: 2.1584x; 1.0386x over previous
//
#include <hip/hip_runtime.h>
#include <hip/hip_bf16.h>

#define D_FEAT 64
#define OVF_CAP 65536

typedef unsigned int uint32;

__device__ inline float blo(uint32 u) { return __uint_as_float(u << 16); }
__device__ inline float bhi(uint32 u) { return __uint_as_float(u & 0xffff0000u); }

// ---- fused: histogram + direct padded-CSR slot write + bf16 cast ----
// t < E:  rk = deg[col[t]]++; rk < C ? slots[col*C+rk]=row : overflow append
// strided: xb[j] = packed bf16x2 of x
__global__ void k_prep(const float2* __restrict__ x2, uint32* __restrict__ xb,
                       const int* __restrict__ row, const int* __restrict__ col,
                       int* __restrict__ deg, int* __restrict__ slots,
                       int2* __restrict__ ovf, int* __restrict__ ovf_cnt,
                       int nhalf, int E, int C) {
    int t = blockIdx.x * blockDim.x + threadIdx.x;
    if (t < E) {
        int c = col[t];
        int r = row[t];
        int rk = atomicAdd(&deg[c], 1);
        if (rk < C) {
            slots[(size_t)c * C + rk] = r;
        } else {
            int o = atomicAdd(ovf_cnt, 1);
            if (o < OVF_CAP) ovf[o] = make_int2(r, c);
        }
    }
    const int stride = gridDim.x * blockDim.x;
    for (int j = t; j < nhalf; j += stride) {
        float2 v = x2[j];
        __hip_bfloat16 bx = __float2bfloat16(v.x);
        __hip_bfloat16 by = __float2bfloat16(v.y);
        uint32 ux = *reinterpret_cast<unsigned short*>(&bx);
        uint32 uy = *reinterpret_cast<unsigned short*>(&by);
        xb[j] = ux | (uy << 16);
    }
}

// ---- dis[i] = deg>0 ? rsqrt(deg) : 0 ----
__global__ void k_dis(const int* __restrict__ deg, float* __restrict__ dis, int n) {
    int i = blockIdx.x * blockDim.x + threadIdx.x;
    if (i < n) {
        int d = deg[i];
        dis[i] = (d > 0) ? rsqrtf((float)d) : 0.0f;
    }
}

// ---- gather v3: one wave per node, 4 edges in parallel, bf16 uint2 loads ----
// lane = (q, l): q = edge slot within quad (lane>>4), l = feat quad (lane&15)
__global__ void k_gather4(const uint32* __restrict__ xb,
                          const float4* __restrict__ x4,
                          const int* __restrict__ deg,
                          const int* __restrict__ slots,
                          const float* __restrict__ dis,
                          const float* __restrict__ alpha_p,
                          const float* __restrict__ rs_p,
                          float4* __restrict__ out4, int n, int C) {
    int wid = (blockIdx.x * blockDim.x + threadIdx.x) >> 6;
    if (wid >= n) return;
    const int lane = threadIdx.x & 63;
    const int q = lane >> 4;
    const int l = lane & 15;
    int d = deg[wid];
    int e = (d < C) ? d : C;
    const int* sl = slots + (size_t)wid * C;
    float ax = 0.f, ay = 0.f, az = 0.f, aw = 0.f;
    int k = 0;
    for (; k + 8 <= e; k += 8) {              // 8 edges/iter (2 per quarter)
        int s0 = sl[k + q];
        int s1 = sl[k + 4 + q];
        float w0 = dis[s0], w1 = dis[s1];
        uint2 p0 = ((const uint2*)(xb + (size_t)s0 * 32))[l];   // feats 4l..4l+3
        uint2 p1 = ((const uint2*)(xb + (size_t)s1 * 32))[l];
        ax = fmaf(w0, blo(p0.x), ax); ay = fmaf(w0, bhi(p0.x), ay);
        az = fmaf(w0, blo(p0.y), az); aw = fmaf(w0, bhi(p0.y), aw);
        ax = fmaf(w1, blo(p1.x), ax); ay = fmaf(w1, bhi(p1.x), ay);
        az = fmaf(w1, blo(p1.y), az); aw = fmaf(w1, bhi(p1.y), aw);
    }
    for (; k < e; k += 4) {                   // 0-7 leftover edges
        int kk = k + q;
        if (kk < e) {
            int s0 = sl[kk];
            float w0 = dis[s0];
            uint2 p0 = ((const uint2*)(xb + (size_t)s0 * 32))[l];
            ax = fmaf(w0, blo(p0.x), ax); ay = fmaf(w0, bhi(p0.x), ay);
            az = fmaf(w0, blo(p0.y), az); aw = fmaf(w0, bhi(p0.y), aw);
        }
    }
    // fold quarters: q0 += q2 (and q1 += q3), then q0 += q1
    ax += __shfl_down(ax, 32, 64); ay += __shfl_down(ay, 32, 64);
    az += __shfl_down(az, 32, 64); aw += __shfl_down(aw, 32, 64);
    ax += __shfl_down(ax, 16, 64); ay += __shfl_down(ay, 16, 64);
    az += __shfl_down(az, 16, 64); aw += __shfl_down(aw, 16, 64);
    if (q == 0) {
        float adw = (*alpha_p) * dis[wid];
        float rs  = *rs_p;
        float4 xr = x4[(size_t)wid * 16 + l];
        float4 o;
        o.x = fmaf(adw, ax, rs * xr.x);
        o.y = fmaf(adw, ay, rs * xr.y);
        o.z = fmaf(adw, az, rs * xr.z);
        o.w = fmaf(adw, aw, rs * xr.w);
        out4[(size_t)wid * 16 + l] = o;
    }
}

// ---- overflow fix-up: out[c][f] += alpha*dis[r]*dis[c]*x[r][f] (fp32) ----
__global__ void k_ovf(const int2* __restrict__ ovf, const int* __restrict__ cnt_p,
                      const float* __restrict__ x, const float* __restrict__ dis,
                      const float* __restrict__ alpha_p, float* __restrict__ out) {
    int cnt = *cnt_p;
    if (cnt > OVF_CAP) cnt = OVF_CAP;
    if (cnt <= 0) return;
    float a = *alpha_p;
    long long total = (long long)cnt * 64;
    long long stride = (long long)gridDim.x * blockDim.x;
    for (long long idx = blockIdx.x * (long long)blockDim.x + threadIdx.x;
         idx < total; idx += stride) {
        int e = (int)(idx >> 6);
        int f = (int)(idx & 63);
        int2 rc = ovf[e];
        float w = a * dis[rc.x] * dis[rc.y];
        atomicAdd(&out[(size_t)rc.y * D_FEAT + f], w * x[(size_t)rc.x * D_FEAT + f]);
    }
}

// ================= fallback (tiny ws): round-1 style atomic scatter =========
__global__ void k_deg_simple(const int* __restrict__ col, int* __restrict__ deg, int E) {
    int e = blockIdx.x * blockDim.x + threadIdx.x;
    if (e < E) atomicAdd(&deg[col[e]], 1);
}
__global__ void k_resid(const float4* __restrict__ x, float4* __restrict__ out,
                        const float* __restrict__ rs_p, int n4) {
    int i = blockIdx.x * blockDim.x + threadIdx.x;
    if (i < n4) {
        float rs = *rs_p;
        float4 v = x[i];
        out[i] = make_float4(rs * v.x, rs * v.y, rs * v.z, rs * v.w);
    }
}
__global__ void k_scatter(const float* __restrict__ x, const int* __restrict__ row,
                          const int* __restrict__ col, const float* __restrict__ dis,
                          const float* __restrict__ alpha_p, float* __restrict__ out, int E) {
    int gid = blockIdx.x * blockDim.x + threadIdx.x;
    int e = gid >> 6, f = gid & 63;
    if (e >= E) return;
    int r = row[e], c = col[e];
    float norm = (*alpha_p) * dis[r] * dis[c];
    atomicAdd(&out[(size_t)c * D_FEAT + f], norm * x[(size_t)r * D_FEAT + f]);
}

extern "C" void kernel_launch(void* const* d_in, const int* in_sizes, int n_in,
                              void* d_out, int out_size, void* d_ws, size_t ws_size,
                              hipStream_t stream) {
    const float* x         = (const float*)d_in[0];
    const float* alpha     = (const float*)d_in[1];
    const float* res_scale = (const float*)d_in[2];
    const int*   ei        = (const int*)d_in[3];

    const int n = in_sizes[0] / D_FEAT;      // 100000
    const int E = in_sizes[3] / 2;           // 1600000
    const int* row = ei;                     // sources
    const int* col = ei + E;                 // targets

    float* out = (float*)d_out;

    // workspace layout: deg[n+1] (deg[n] = overflow counter), dis[n],
    //                   ovf[OVF_CAP], xb[n*32], slots[n*C]
    const size_t fixed = (size_t)(n + 1) * 4 + (size_t)n * 4 +
                         (size_t)OVF_CAP * 8 + (size_t)n * 128;
    int C = 0;
    if (ws_size > fixed) {
        size_t c_avail = (ws_size - fixed) / ((size_t)n * 4);
        C = (c_avail > 64) ? 64 : (int)c_avail;
    }

    char* wsp = (char*)d_ws;
    int*    deg  = (int*)wsp;      wsp += (size_t)(n + 1) * 4;
    float*  dis  = (float*)wsp;    wsp += (size_t)n * 4;
    int2*   ovf  = (int2*)wsp;     wsp += (size_t)OVF_CAP * 8;
    uint32* xb   = (uint32*)wsp;   wsp += (size_t)n * 128;
    int*    slots = (int*)wsp;
    int*    ovf_cnt = deg + n;

    const int nhalf = n * (D_FEAT / 2);

    if (C >= 24) {
        // ---- padded-CSR path ----
        hipMemsetAsync(deg, 0, (size_t)(n + 1) * sizeof(int), stream);
        k_prep<<<(E + 255) / 256, 256, 0, stream>>>(
            (const float2*)x, xb, row, col, deg, slots, ovf, ovf_cnt,
            nhalf, E, C);
        k_dis<<<(n + 255) / 256, 256, 0, stream>>>(deg, dis, n);
        const long long total = (long long)n * D_FEAT;
        const int blocks = (int)((total + 255) / 256);
        k_gather4<<<blocks, 256, 0, stream>>>(xb, (const float4*)x, deg, slots,
                                              dis, alpha, res_scale,
                                              (float4*)out, n, C);
        k_ovf<<<64, 256, 0, stream>>>(ovf, ovf_cnt, x, dis, alpha, out);
    } else {
        // ---- fallback: atomic scatter (needs only deg+dis) ----
        hipMemsetAsync(deg, 0, (size_t)(n + 1) * sizeof(int), stream);
        k_deg_simple<<<(E + 255) / 256, 256, 0, stream>>>(col, deg, E);
        k_dis<<<(n + 255) / 256, 256, 0, stream>>>(deg, dis, n);
        const int n4 = n * D_FEAT / 4;
        k_resid<<<(n4 + 255) / 256, 256, 0, stream>>>((const float4*)x,
                                                      (float4*)out, res_scale, n4);
        const long long total = (long long)E * D_FEAT;
        const int blocks = (int)((total + 255) / 256);
        k_scatter<<<blocks, 256, 0, stream>>>(x, row, col, dis, alpha, out, E);
    }
}